// Round 11
// baseline (1640.636 us; speedup 1.0000x reference)
//
#include <hip/hip_runtime.h>

// Neural-ODE RK4 over MLP 12->300->100->50->12, B=1024, T=100.
// 256 blocks x 512 threads (8 waves), 4 batch elements per block, 1 block/CU.
// R11: DS-pipe diet. Evidence R4 vs R9: dur tracks DS-instruction count
// (~8-12 cyc each on the shared LDS pipe), not VALU. So:
//  - L2: ONE strided ds_read_b128 per wave (lane i holds h1T[kbase+i][0..3]),
//    then v_readlane (VALU, SGPR broadcast) + scalar FMA. 368 -> 72 DS.
//  - Tail is wave-local (wave e = elem e): h2 never touches LDS (readlane
//    from the reducing lanes' registers), in-wave h3e round trip, RK4 state
//    (xreg, ks) in registers. 3 barriers/eval (A: h1T, B: pL2, C: state).
// W2 in regs (76/thread); W1/W3/W4 in LDS; DS/eval ~470 vs R10's ~840.

typedef float v2f __attribute__((ext_vector_type(2)));
typedef float v4f __attribute__((ext_vector_type(4)));

constexpr int TT = 100;
constexpr int D  = 12;
constexpr int H1 = 300;
constexpr int H2 = 100;
constexpr int H3 = 50;
constexpr float NEG = 0.01f;

__device__ __forceinline__ float lrelu(float x) { return fmaxf(x, NEG * x); }
__device__ __forceinline__ float rdlane(float v, int lane) {
    return __int_as_float(__builtin_amdgcn_readlane(__float_as_int(v), lane));
}

__global__ __launch_bounds__(512)
void node_rk4_kernel(const float* __restrict__ y0, const float* __restrict__ t,
                     const float* __restrict__ W1, const float* __restrict__ b1,
                     const float* __restrict__ W2, const float* __restrict__ b2,
                     const float* __restrict__ W3, const float* __restrict__ b3,
                     const float* __restrict__ W4, const float* __restrict__ b4,
                     float* __restrict__ out)
{
    // LDS ~ 54 KB
    __shared__ __align__(16) float sW1 [D * H1];    // [k][j] lane-contiguous
    __shared__ __align__(16) float sW3c[25 * 200];  // [c][j][4k] chunked W3
    __shared__ __align__(16) float sW4 [52 * 12];   // [k][j], rows 50,51 zero
    __shared__ __align__(16) float h1T [304 * 4];   // [k][e], k=300..303 zero
    __shared__ __align__(16) float pL2 [32 * 104];  // [(w*4+e)][104]
    __shared__ __align__(16) float h3e [4 * 52];    // [e][52], cols 50,51 zero
    __shared__ __align__(16) float sx  [48];
    __shared__ __align__(16) float sxe [48];
    __shared__ float st [100];

    const int tid = threadIdx.x;
    const int l   = tid & 63;
    const int w   = tid >> 6;            // wave 0..7 = L2 k-eighth
    const bool l2act = (l < 50);
    const bool tw    = (w < 4);          // tail wave: elem e = w

    // ---- W2 in regs: wave w owns k = w*38 .. w*38+37; lane l owns cols l, l+50 ----
    float w2a[38], w2b[38];
#pragma unroll
    for (int i = 0; i < 38; ++i) {
        const int k = w * 38 + i;
        float va = 0.0f, vb = 0.0f;
        if (l2act && k < H1) { va = W2[k * H2 + l]; vb = W2[k * H2 + l + 50]; }
        w2a[i] = va; w2b[i] = vb;
    }

    // ---- L1: thread j<300 owns col j; bias in reg, weights from LDS ----
    const bool l1act = (tid < H1);
    const float rb1 = l1act ? b1[tid] : 0.0f;

    // ---- tail constants ----
    float rb2a = 0.f, rb2b = 0.f, rb3 = 0.f;
    if (tw && l2act) { rb2a = b2[l]; rb2b = b2[l + 50]; rb3 = b3[l]; }
    const int j4 = l >> 2, kq4 = l & 3;             // L4 mapping (lanes < 48)
    const float b4v = (tw && l < 48) ? b4[j4] : 0.0f;

    // ---- one-time LDS staging ----
    for (int i = tid; i < D * H1; i += 512) sW1[i] = W1[i];          // [k][j]
    for (int i = tid; i < H2 * H3; i += 512) {      // W3 [k=100][j=50] -> chunked
        const int k = i / H3, j = i - k * H3;
        sW3c[(k >> 2) * 200 + j * 4 + (k & 3)] = W3[i];
    }
    for (int i = tid; i < 52 * 12; i += 512) sW4[i] = (i < H3 * D) ? W4[i] : 0.0f;
    if (tid < TT) st[tid] = t[tid];                 // t row 0 (uniform over batch)
    if (tid >= 104 && tid < 120) h1T[300 * 4 + (tid - 104)] = 0.0f;  // k=300..303
    if (tid >= 120 && tid < 128) {                  // h3e cols 50,51 zero
        const int u = tid - 120;
        h3e[(u >> 1) * 52 + 50 + (u & 1)] = 0.0f;
    }
    if (tid < 48) {                                 // x0 = y0[:,0,:]; out[:,0,:]
        const int e = tid / 12, j = tid - e * 12;
        const int g = (blockIdx.x * 4 + e) * (TT * D) + j;
        const float v = y0[g];
        sx[tid] = v;
        out[g]  = v;
    }
    __syncthreads();

    // RK4 state in registers of lane (kq4==0, j4) of tail wave e
    float xreg = 0.0f, ks = 0.0f;
    if (tw && l < 48 && kq4 == 0) xreg = sx[w * 12 + j4];

    for (int s = 0; s < TT - 1; ++s) {
        const float dt = st[s + 1] - st[s];
#pragma unroll 1
        for (int ev = 0; ev < 4; ++ev) {
            const float* xin = ev ? sxe : sx;

            // ===== L1: 12 -> 300, col = tid, writes h1T[j][0..3] =====
            if (l1act) {
                float wv[12];
#pragma unroll
                for (int k = 0; k < 12; ++k) wv[k] = sW1[k * H1 + tid];
                v4f r;
#pragma unroll
                for (int e = 0; e < 4; ++e) {
                    const v4f x0 = *(const v4f*)(xin + e * 12);
                    const v4f x1 = *(const v4f*)(xin + e * 12 + 4);
                    const v4f x2 = *(const v4f*)(xin + e * 12 + 8);
                    float a = rb1;
                    a = fmaf(x0.x, wv[0], a);  a = fmaf(x0.y, wv[1], a);
                    a = fmaf(x0.z, wv[2], a);  a = fmaf(x0.w, wv[3], a);
                    a = fmaf(x1.x, wv[4], a);  a = fmaf(x1.y, wv[5], a);
                    a = fmaf(x1.z, wv[6], a);  a = fmaf(x1.w, wv[7], a);
                    a = fmaf(x2.x, wv[8], a);  a = fmaf(x2.y, wv[9], a);
                    a = fmaf(x2.z, wv[10], a); a = fmaf(x2.w, wv[11], a);
                    r[e] = lrelu(a);
                }
                *(v4f*)(h1T + tid * 4) = r;
            }
            __syncthreads();                        // A: h1T ready

            // ===== L2: ONE strided b128 read + readlane broadcast + scalar FMA =====
            {
                const int ksrc = w * 38 + ((l < 38) ? l : 37);
                const v4f hv = *(const v4f*)(h1T + ksrc * 4);   // lane i: k=kbase+i
                float a0A = 0.f, a0B = 0.f, a1A = 0.f, a1B = 0.f;
                float a2A = 0.f, a2B = 0.f, a3A = 0.f, a3B = 0.f;
#pragma unroll
                for (int i = 0; i < 38; ++i) {
                    const float h0 = rdlane(hv[0], i);
                    const float h1 = rdlane(hv[1], i);
                    const float h2 = rdlane(hv[2], i);
                    const float h3 = rdlane(hv[3], i);
                    a0A = fmaf(h0, w2a[i], a0A);  a0B = fmaf(h0, w2b[i], a0B);
                    a1A = fmaf(h1, w2a[i], a1A);  a1B = fmaf(h1, w2b[i], a1B);
                    a2A = fmaf(h2, w2a[i], a2A);  a2B = fmaf(h2, w2b[i], a2B);
                    a3A = fmaf(h3, w2a[i], a3A);  a3B = fmaf(h3, w2b[i], a3B);
                }
                if (l2act) {
                    pL2[(w * 4 + 0) * 104 + l]      = a0A;
                    pL2[(w * 4 + 1) * 104 + l]      = a1A;
                    pL2[(w * 4 + 2) * 104 + l]      = a2A;
                    pL2[(w * 4 + 3) * 104 + l]      = a3A;
                    pL2[(w * 4 + 0) * 104 + l + 50] = a0B;
                    pL2[(w * 4 + 1) * 104 + l + 50] = a1B;
                    pL2[(w * 4 + 2) * 104 + l + 50] = a2B;
                    pL2[(w * 4 + 3) * 104 + l + 50] = a3B;
                }
            }
            __syncthreads();                        // B: pL2 ready

            // ===== wave-local tail: wave e = elem e (reduce + L3 + L4 + RK4) =====
            if (tw) {
                const int e = w;
                if (l2act) {
                    // reduce 8 partials -> h2 held in registers (h2a = col l, h2b = col l+50)
                    float va = rb2a, vb = rb2b;
#pragma unroll
                    for (int q = 0; q < 8; ++q) {
                        va += pL2[(q * 4 + e) * 104 + l];
                        vb += pL2[(q * 4 + e) * 104 + l + 50];
                    }
                    const float h2a = lrelu(va);
                    const float h2b = lrelu(vb);
                    // L3: col = l; activations via readlane from lanes' h2a/h2b regs
                    float acc = rb3;
#pragma unroll
                    for (int c = 0; c < 25; ++c) {
                        const v4f wv = *(const v4f*)(sW3c + c * 200 + l * 4);
#pragma unroll
                        for (int q = 0; q < 4; ++q) {
                            const int kk = 4 * c + q;   // compile-time constant
                            const float h = (kk < 50) ? rdlane(h2a, kk)
                                                      : rdlane(h2b, kk - 50);
                            acc = fmaf(h, wv[q], acc);
                        }
                    }
                    h3e[e * 52 + l] = lrelu(acc);   // in-wave write->read below
                }
                // L4: lanes<48, (j4, kq4) split + shfl reduce, fused RK4
                if (l < 48) {
                    const int kb = kq4 * 13;
                    float a = 0.0f;
#pragma unroll
                    for (int i = 0; i < 13; ++i)    // k<=51: pads are zero
                        a = fmaf(h3e[e * 52 + kb + i], sW4[(kb + i) * 12 + j4], a);
                    a += __shfl_xor(a, 1);
                    a += __shfl_xor(a, 2);
                    if (kq4 == 0) {
                        a += b4v;
                        const int bi = e * 12 + j4;
                        if (ev == 0)      { ks = a;          sxe[bi] = xreg + 0.5f * dt * a; }
                        else if (ev == 1) { ks += 2.f * a;   sxe[bi] = xreg + 0.5f * dt * a; }
                        else if (ev == 2) { ks += 2.f * a;   sxe[bi] = xreg + dt * a; }
                        else {
                            const float xn = xreg + dt * (1.0f / 6.0f) * (ks + a);
                            xreg = xn;
                            sx[bi] = xn;
                            out[(blockIdx.x * 4 + e) * (TT * D) + (s + 1) * D + j4] = xn;
                        }
                    }
                }
            }
            __syncthreads();                        // C: state ready
        }
    }
}

extern "C" void kernel_launch(void* const* d_in, const int* in_sizes, int n_in,
                              void* d_out, int out_size, void* d_ws, size_t ws_size,
                              hipStream_t stream) {
    const float* y0 = (const float*)d_in[0];
    const float* t  = (const float*)d_in[1];
    const float* W1 = (const float*)d_in[2];
    const float* b1 = (const float*)d_in[3];
    const float* W2 = (const float*)d_in[4];
    const float* b2 = (const float*)d_in[5];
    const float* W3 = (const float*)d_in[6];
    const float* b3 = (const float*)d_in[7];
    const float* W4 = (const float*)d_in[8];
    const float* b4 = (const float*)d_in[9];
    float* out = (float*)d_out;

    node_rk4_kernel<<<256, 512, 0, stream>>>(y0, t, W1, b1, W2, b2, W3, b3, W4, b4, out);
}